// Round 3
// baseline (642.328 us; speedup 1.0000x reference)
//
#include <hip/hip_runtime.h>
#include <hip/hip_bf16.h>

// Problem constants (B=4, N=2048, D_IN=768, H=12, D_HEAD=64)
#define NSEQ 2048
#define DIN  768
#define NH   12

typedef __attribute__((ext_vector_type(8))) short bf16x8;
typedef __attribute__((ext_vector_type(4))) short short4v;
typedef __attribute__((ext_vector_type(4))) float f32x4;

__device__ __forceinline__ unsigned short f2bf(float f) {
    unsigned u = __builtin_bit_cast(unsigned, f);
    u += 0x7FFFu + ((u >> 16) & 1u);   // RNE
    return (unsigned short)(u >> 16);
}

// ---------------- cast kernels ----------------
__global__ __launch_bounds__(256) void cast_x_k(const float* __restrict__ x,
                                                short* __restrict__ xb, int n4) {
    int i = blockIdx.x * 256 + threadIdx.x;
    if (i >= n4) return;
    float4 v = ((const float4*)x)[i];
    short4v o;
    o[0] = (short)f2bf(v.x); o[1] = (short)f2bf(v.y);
    o[2] = (short)f2bf(v.z); o[3] = (short)f2bf(v.w);
    ((short4v*)xb)[i] = o;
}

// WT[c][k], c = m*768 + h*64 + e  (m in {q,k,v}), source W[h][k][e]
__global__ __launch_bounds__(256) void cast_wqkv_k(const float* __restrict__ Wq,
                                                   const float* __restrict__ Wk,
                                                   const float* __restrict__ Wv,
                                                   short* __restrict__ wt) {
    int tid = blockIdx.x * 256 + threadIdx.x;  // 2304*96 threads
    int c = tid / 96;
    int k0 = (tid % 96) * 8;
    int m = c / 768, rem = c - m * 768;
    const float* W = (m == 0) ? Wq : ((m == 1) ? Wk : Wv);
    const float* src = W + (rem >> 6) * (768 * 64) + (rem & 63);
    bf16x8 o;
    #pragma unroll
    for (int j = 0; j < 8; ++j) o[j] = (short)f2bf(src[(k0 + j) * 64]);
    *(bf16x8*)(wt + (size_t)c * 768 + k0) = o;
}

// WoT[c][k] = Wo[k][c]
__global__ __launch_bounds__(256) void cast_wo_k(const float* __restrict__ Wo,
                                                 short* __restrict__ wto) {
    int tid = blockIdx.x * 256 + threadIdx.x;  // 768*96 threads
    int c = tid / 96;
    int k0 = (tid % 96) * 8;
    bf16x8 o;
    #pragma unroll
    for (int j = 0; j < 8; ++j) o[j] = (short)f2bf(Wo[(size_t)(k0 + j) * 768 + c]);
    *(bf16x8*)(wto + (size_t)c * 768 + k0) = o;
}

// ---------------- GEMM: C[M][N] = A[M][768] * Bt[N][768]^T ----------------
template<int BM, int BN, int MODE>
__global__ __launch_bounds__(256)
void gemm_bf16(const short* __restrict__ A, const short* __restrict__ Bt,
               short* __restrict__ qk, short* __restrict__ vT,
               const float* __restrict__ bq, const float* __restrict__ bk,
               const float* __restrict__ bv,
               float* __restrict__ outf, const float* __restrict__ bo)
{
    constexpr int K = 768;
    constexpr int WM = BM / 32;
    constexpr int WN = BN / 32;
    const int lane = threadIdx.x & 63;
    const int wid  = threadIdx.x >> 6;
    const int l15 = lane & 15, lg = lane >> 4;
    const int wm = wid >> 1, wn = wid & 1;
    const int row0 = blockIdx.x * BM + wm * (BM / 2);
    const int col0 = blockIdx.y * BN + wn * (BN / 2);

    f32x4 acc[WM][WN];
    #pragma unroll
    for (int i = 0; i < WM; ++i)
        #pragma unroll
        for (int j = 0; j < WN; ++j) acc[i][j] = (f32x4){0.f, 0.f, 0.f, 0.f};

    const short* Ap = A  + (size_t)(row0 + l15) * K + lg * 8;
    const short* Bp = Bt + (size_t)(col0 + l15) * K + lg * 8;

    #pragma unroll 2
    for (int k0 = 0; k0 < K; k0 += 32) {
        bf16x8 a[WM], b[WN];
        #pragma unroll
        for (int i = 0; i < WM; ++i) a[i] = *(const bf16x8*)(Ap + i * 16 * K + k0);
        #pragma unroll
        for (int j = 0; j < WN; ++j) b[j] = *(const bf16x8*)(Bp + j * 16 * K + k0);
        #pragma unroll
        for (int i = 0; i < WM; ++i)
            #pragma unroll
            for (int j = 0; j < WN; ++j)
                acc[i][j] = __builtin_amdgcn_mfma_f32_16x16x32_bf16(a[i], b[j], acc[i][j], 0, 0, 0);
    }

    if (MODE == 0) {
        #pragma unroll
        for (int i = 0; i < WM; ++i) {
            const int rowb = row0 + i * 16 + lg * 4;
            #pragma unroll
            for (int j = 0; j < WN; ++j) {
                const int col = col0 + j * 16 + l15;
                const int m = col / 768;
                const int rem = col - m * 768;           // h*64 + e
                const float bias = ((m == 0) ? bq : (m == 1) ? bk : bv)[rem];
                if (m < 2) {
                    const float sc = (m == 0) ? 0.125f : 1.0f;
                    #pragma unroll
                    for (int r = 0; r < 4; ++r) {
                        float v = (acc[i][j][r] + bias) * sc;
                        qk[(size_t)(rowb + r) * 1536 + col] = (short)f2bf(v);
                    }
                } else {
                    short4v pk;
                    #pragma unroll
                    for (int r = 0; r < 4; ++r) pk[r] = (short)f2bf(acc[i][j][r] + bias);
                    const int bb = rowb >> 11;
                    const int n0 = rowb & 2047;
                    *(short4v*)(vT + ((size_t)(bb * 768 + rem)) * 2048 + n0) = pk;
                }
            }
        }
    } else {
        #pragma unroll
        for (int i = 0; i < WM; ++i) {
            const int rowb = row0 + i * 16 + lg * 4;
            #pragma unroll
            for (int j = 0; j < WN; ++j) {
                const int col = col0 + j * 16 + l15;
                const float bias = bo[col];
                #pragma unroll
                for (int r = 0; r < 4; ++r)
                    outf[(size_t)(rowb + r) * 768 + col] = acc[i][j][r] + bias;
            }
        }
    }
}

// ---------------- flash attention (swapped-operand form) ----------------
// S^T = mfma(K, Q): lane holds q = l15 column; kv = cf*16 + lg*4 + r in regs.
// Softmax: in-lane tree + 2 shfl_xor (lg groups); m/l are ONE scalar per lane.
// O^T = mfma(V^T, P^T): cols q = l15 -> rescale needs no redistribution.
// P^T -> LDS as 4x ds_write_b64, read back as 2x ds_read_b128 (B-frag).
// K double-buffered (prefetch next tile during softmax); V issued early.
__global__ __launch_bounds__(256)
void attn_k(const short* __restrict__ qk, const short* __restrict__ vT,
            short* __restrict__ ctx)
{
    __shared__ short Plds[4][16][72];   // [wave][q][kv(+pad)]
    const int lane = threadIdx.x & 63;
    const int wid  = threadIdx.x >> 6;
    const int l15 = lane & 15, lg = lane >> 4;
    const int bid = blockIdx.x;
    const int qblk = bid & 31;
    const int bh = bid >> 5;
    const int b = bh / NH, h = bh - b * NH;
    const int q0 = qblk * 64 + wid * 16;

    const short* qp = qk + (size_t)b * (NSEQ * 1536) + h * 64;   // q[n][e]
    const short* kp = qp + 768;                                   // k[n][e]
    const short* vp = vT + (size_t)(b * 768 + h * 64) * NSEQ;     // vT[e][n]

    // Q as B-fragment: col = l15 = q, k(e) = kk*32 + lg*8 + j
    bf16x8 qfb[2];
    #pragma unroll
    for (int kk = 0; kk < 2; ++kk)
        qfb[kk] = *(const bf16x8*)(qp + (size_t)(q0 + l15) * 1536 + kk * 32 + lg * 8);

    f32x4 o[4];
    #pragma unroll
    for (int i = 0; i < 4; ++i) o[i] = (f32x4){0.f, 0.f, 0.f, 0.f};
    float m_run = -1e30f, l_run = 0.f;

    // K as A-fragment: row = l15 -> kv, k(e) contiguous
    bf16x8 kaA[4][2], kaB[4][2];
    #pragma unroll
    for (int cf = 0; cf < 4; ++cf)
        #pragma unroll
        for (int kk = 0; kk < 2; ++kk)
            kaA[cf][kk] = *(const bf16x8*)(kp + (size_t)(cf * 16 + l15) * 1536 + kk * 32 + lg * 8);

#define ATTN_TILE(KA, KB, KV0)                                                              \
    {                                                                                       \
        const int kv0_ = (KV0);                                                             \
        f32x4 st[4];                                                                        \
        __builtin_amdgcn_s_setprio(1);                                                      \
        _Pragma("unroll")                                                                   \
        for (int cf = 0; cf < 4; ++cf) {                                                    \
            st[cf] = __builtin_amdgcn_mfma_f32_16x16x32_bf16(KA[cf][0], qfb[0],             \
                         (f32x4){0.f, 0.f, 0.f, 0.f}, 0, 0, 0);                             \
            st[cf] = __builtin_amdgcn_mfma_f32_16x16x32_bf16(KA[cf][1], qfb[1],             \
                         st[cf], 0, 0, 0);                                                  \
        }                                                                                   \
        __builtin_amdgcn_s_setprio(0);                                                      \
        const int kvn_ = (kv0_ + 64) & (NSEQ - 1);                                          \
        _Pragma("unroll")                                                                   \
        for (int cf = 0; cf < 4; ++cf) {                                                    \
            KB[cf][0] = *(const bf16x8*)(kp + (size_t)(kvn_ + cf * 16 + l15) * 1536 + lg * 8);        \
            KB[cf][1] = *(const bf16x8*)(kp + (size_t)(kvn_ + cf * 16 + l15) * 1536 + 32 + lg * 8);   \
        }                                                                                   \
        bf16x8 vb[4][2];                                                                    \
        _Pragma("unroll")                                                                   \
        for (int et = 0; et < 4; ++et) {                                                    \
            vb[et][0] = *(const bf16x8*)(vp + (size_t)(et * 16 + l15) * 2048 + kv0_ + lg * 8);        \
            vb[et][1] = *(const bf16x8*)(vp + (size_t)(et * 16 + l15) * 2048 + kv0_ + 32 + lg * 8);   \
        }                                                                                   \
        float x0 = fmaxf(fmaxf(st[0][0], st[0][1]), fmaxf(st[0][2], st[0][3]));             \
        float x1 = fmaxf(fmaxf(st[1][0], st[1][1]), fmaxf(st[1][2], st[1][3]));             \
        float x2 = fmaxf(fmaxf(st[2][0], st[2][1]), fmaxf(st[2][2], st[2][3]));             \
        float x3 = fmaxf(fmaxf(st[3][0], st[3][1]), fmaxf(st[3][2], st[3][3]));             \
        float mx = fmaxf(fmaxf(x0, x1), fmaxf(x2, x3));                                     \
        mx = fmaxf(mx, __shfl_xor(mx, 16, 64));                                             \
        mx = fmaxf(mx, __shfl_xor(mx, 32, 64));                                             \
        const float mn_ = fmaxf(m_run, mx);                                                 \
        const float al_ = __expf(m_run - mn_);                                              \
        m_run = mn_;                                                                        \
        float p[4][4];                                                                      \
        _Pragma("unroll")                                                                   \
        for (int cf = 0; cf < 4; ++cf)                                                      \
            _Pragma("unroll")                                                               \
            for (int r = 0; r < 4; ++r) p[cf][r] = __expf(st[cf][r] - mn_);                 \
        float s0 = (p[0][0] + p[0][1]) + (p[0][2] + p[0][3]);                               \
        float s1 = (p[1][0] + p[1][1]) + (p[1][2] + p[1][3]);                               \
        float s2 = (p[2][0] + p[2][1]) + (p[2][2] + p[2][3]);                               \
        float s3 = (p[3][0] + p[3][1]) + (p[3][2] + p[3][3]);                               \
        float ts = (s0 + s1) + (s2 + s3);                                                   \
        ts += __shfl_xor(ts, 16, 64);                                                       \
        ts += __shfl_xor(ts, 32, 64);                                                       \
        l_run = l_run * al_ + ts;                                                           \
        _Pragma("unroll")                                                                   \
        for (int et = 0; et < 4; ++et)                                                      \
            _Pragma("unroll")                                                               \
            for (int r = 0; r < 4; ++r) o[et][r] *= al_;                                    \
        _Pragma("unroll")                                                                   \
        for (int cf = 0; cf < 4; ++cf) {                                                    \
            short4v pk;                                                                     \
            _Pragma("unroll")                                                               \
            for (int r = 0; r < 4; ++r) pk[r] = (short)f2bf(p[cf][r]);                      \
            *(short4v*)&Plds[wid][l15][cf * 16 + lg * 4] = pk;                              \
        }                                                                                   \
        asm volatile("s_waitcnt lgkmcnt(0)" ::: "memory");                                  \
        __builtin_amdgcn_sched_barrier(0);                                                  \
        bf16x8 pb0 = *(const bf16x8*)&Plds[wid][l15][lg * 8];                               \
        bf16x8 pb1 = *(const bf16x8*)&Plds[wid][l15][32 + lg * 8];                          \
        asm volatile("s_waitcnt lgkmcnt(0)" ::: "memory");                                  \
        __builtin_amdgcn_sched_barrier(0);                                                  \
        __builtin_amdgcn_s_setprio(1);                                                      \
        _Pragma("unroll")                                                                   \
        for (int et = 0; et < 4; ++et) {                                                    \
            o[et] = __builtin_amdgcn_mfma_f32_16x16x32_bf16(vb[et][0], pb0, o[et], 0, 0, 0);\
            o[et] = __builtin_amdgcn_mfma_f32_16x16x32_bf16(vb[et][1], pb1, o[et], 0, 0, 0);\
        }                                                                                   \
        __builtin_amdgcn_s_setprio(0);                                                      \
    }

    #pragma unroll 1
    for (int t0 = 0; t0 < NSEQ; t0 += 128) {
        ATTN_TILE(kaA, kaB, t0)
        ATTN_TILE(kaB, kaA, t0 + 64)
    }
#undef ATTN_TILE

    const float inv = 1.0f / l_run;
    #pragma unroll
    for (int et = 0; et < 4; ++et) {
        short4v ov;
        #pragma unroll
        for (int r = 0; r < 4; ++r) ov[r] = (short)f2bf(o[et][r] * inv);
        *(short4v*)&ctx[(size_t)(b * NSEQ + q0 + l15) * 768 + h * 64 + et * 16 + lg * 4] = ov;
    }
}

// ---------------- launch ----------------
extern "C" void kernel_launch(void* const* d_in, const int* in_sizes, int n_in,
                              void* d_out, int out_size, void* d_ws, size_t ws_size,
                              hipStream_t stream) {
    (void)in_sizes; (void)n_in; (void)out_size; (void)ws_size;
    const float* x  = (const float*)d_in[0];
    const float* Wq = (const float*)d_in[1];
    const float* bq = (const float*)d_in[2];
    const float* Wk = (const float*)d_in[3];
    const float* bk = (const float*)d_in[4];
    const float* Wv = (const float*)d_in[5];
    const float* bv = (const float*)d_in[6];
    const float* Wo = (const float*)d_in[7];
    const float* bo = (const float*)d_in[8];
    float* out = (float*)d_out;

    char* ws = (char*)d_ws;
    short* xb  = (short*)(ws);             // x bf16            12,582,912 B
    short* wt  = (short*)(ws + 12582912);  // WT[2304][768]      3,538,944 B
    short* wto = (short*)(ws + 16121856);  // WoT[768][768]      1,179,648 B
    short* qk  = (short*)(ws + 17301504);  // q|k [8192][1536]  25,165,824 B
    short* vT  = (short*)(ws + 42467328);  // vT[3072][2048]    12,582,912 B
    short* ctx = (short*)(ws + 55050240);  // ctx [8192][768]   12,582,912 B

    cast_x_k   <<<6144, 256, 0, stream>>>(x, xb, (4 * NSEQ * DIN) / 4);
    cast_wqkv_k<<< 864, 256, 0, stream>>>(Wq, Wk, Wv, wt);
    cast_wo_k  <<< 288, 256, 0, stream>>>(Wo, wto);

    // QKV projection: M=8192, N=2304, K=768
    gemm_bf16<128, 128, 0><<<dim3(64, 18), 256, 0, stream>>>(
        xb, wt, qk, vT, bq, bk, bv, nullptr, nullptr);

    // attention: 48 (b,h) x 32 q-chunks
    attn_k<<<48 * 32, 256, 0, stream>>>(qk, vT, ctx);

    // output projection: M=8192, N=768, K=768
    gemm_bf16<64, 128, 1><<<dim3(128, 6), 256, 0, stream>>>(
        ctx, wto, nullptr, nullptr, nullptr, nullptr, nullptr, out, bo);
}